// Round 12
// baseline (105.888 us; speedup 1.0000x reference)
//
#include <hip/hip_runtime.h>
#include <hip/hip_fp16.h>

#define CELL 128
#define STEPS 20

typedef _Float16 half8_t __attribute__((ext_vector_type(8)));
typedef float    floatx4 __attribute__((ext_vector_type(4)));

__device__ __forceinline__ unsigned packf2(float x, float y) {
    typedef _Float16 h2 __attribute__((ext_vector_type(2)));
    h2 h = { (_Float16)x, (_Float16)y };
    return __builtin_bit_cast(unsigned, h);
}
__device__ __forceinline__ float fdot2u(unsigned a, unsigned b, float c) {
    typedef _Float16 h2 __attribute__((ext_vector_type(2)));
#if __has_builtin(__builtin_amdgcn_fdot2)
    return __builtin_amdgcn_fdot2(__builtin_bit_cast(h2, a), __builtin_bit_cast(h2, b), c, false);
#else
    h2 x = __builtin_bit_cast(h2, a), y = __builtin_bit_cast(h2, b);
    return fmaf((float)x[0], (float)y[0], fmaf((float)x[1], (float)y[1], c));
#endif
}
__device__ __forceinline__ float fast_sigmoid(float x) { return 1.0f / (1.0f + __expf(-x)); }
__device__ __forceinline__ float fast_tanh(float x) {
    return 2.0f / (1.0f + __expf(-2.0f * x)) - 1.0f;
}

// ===== ws layout =====
// [0, 131072)            : W_hh B-fragments, f16, 8192 uint4 (frag spec below)
// [131072, 131072+40960) : gates_x f32[20][512] = W_ih . x(t) + b_ih + b_hh
//   x(0)=emb_start; x(t)=emb_keys[key(t-1), net(t-1)]  (R10/R11 had t,t+1 — BUG, fixed)
//
// frag spec (consumed by main thread t0 in [0,512)):
//   wv=t0>>6, lane=t0&63, quad=lane>>4, lcol=lane&15
//   tile tau in [0,4) = gate block (i,f,g,o); row r = tau*128 + wv*16 + lcol
//   chunk kc in [0,4): k0 = kc*32 + quad*8 -> W_hh[r][k0..k0+7]
//   frag index F = t0*16 + kc*4 + tau

__global__ void __launch_bounds__(256)
nas_conv_kernel(const float* __restrict__ W_ih, const float* __restrict__ W_hh,
                const float* __restrict__ b_ih, const float* __restrict__ b_hh,
                const float* __restrict__ emb_start, const float* __restrict__ emb_keys,
                const int* __restrict__ net,
                uint4* __restrict__ wsf, float* __restrict__ wsg)
{
    const int tid = blockIdx.x * 256 + threadIdx.x;      // 0..8191
    // ---- W_hh h-part fragments (one per thread) ----
    {
        const int f = tid;
        const int t0 = f >> 4, rem = f & 15, kc = rem >> 2, tau = rem & 3;
        const int wv = t0 >> 6, lane = t0 & 63, quad = lane >> 4, lcol = lane & 15;
        const int r  = tau * 128 + wv * 16 + lcol;
        const int k0 = kc * 32 + quad * 8;
        const float4* s4 = (const float4*)(W_hh + r * CELL + k0);
        float4 a = s4[0], b = s4[1];
        half8_t h = { (_Float16)a.x, (_Float16)a.y, (_Float16)a.z, (_Float16)a.w,
                      (_Float16)b.x, (_Float16)b.y, (_Float16)b.z, (_Float16)b.w };
        wsf[f] = __builtin_bit_cast(uint4, h);
    }
    // ---- gates_x[t][r] in fp32 (x-path exact; recurrence-independent) ----
    for (int f = tid; f < STEPS * 512; f += 8192) {
        const int t = f >> 9, r = f & 511;
        const float* x = (t == 0) ? emb_start
                       : emb_keys + ((((t - 1) & 3) * 6) + net[t - 1]) * CELL;
        const float4* xr = (const float4*)x;
        const float4* wr = (const float4*)(W_ih + r * CELL);
        float a0 = 0.f, a1 = 0.f, a2 = 0.f, a3 = 0.f;
#pragma unroll
        for (int q = 0; q < 32; ++q) {
            float4 w = wr[q], v = xr[q];
            a0 = fmaf(w.x, v.x, a0); a1 = fmaf(w.y, v.y, a1);
            a2 = fmaf(w.z, v.z, a2); a3 = fmaf(w.w, v.w, a3);
        }
        wsg[f] = (a0 + a1) + (a2 + a3) + b_ih[r] + b_hh[r];
    }
}

// One 512-thread workgroup, ONE barrier per step.
// Wave wv owns cells wv*16..wv*16+15: its 4 MFMA tiles are the 4 gate blocks
// for those cells, so the LSTM elementwise is wave-local (no gates round-trip,
// no second barrier). In-loop MFMA is h-part only (K=128, 4 broadcast
// ds_read_b128 + 16 MFMA; 64 weight dwords/lane -> no spill at 8 waves).
// Heads of step t-1 run on waves 6,7 lanes 16-63 (6 groups of 16 lanes);
// all softmaxes + out stores deferred to the epilogue (no vmcnt at barriers).
extern "C" __global__ void __launch_bounds__(512, 1)
nas_policy_kernel(const float* __restrict__ fc_W,       // [4][6][128]
                  const float* __restrict__ fc_b,       // [4][6]
                  const uint4* __restrict__ wsf,        // [8192] W_hh frags
                  const float* __restrict__ wsg,        // [20][512] gates_x
                  float* __restrict__ out)              // [20][1][6] fp32
{
    const int t0   = threadIdx.x;    // 0..511
    const int wv   = t0 >> 6;
    const int lane = t0 & 63;
    const int quad = lane >> 4;

    __shared__ __align__(16) unsigned hbuf[2 * 64];     // h packed half2, parity-buffered
    __shared__ __align__(16) float    s_gx[STEPS * 512];// gates_x staged (40 KB)
    __shared__ unsigned s_fcw2[24 * 64];                // fc_W packed half2
    __shared__ float    s_fcb[24];
    __shared__ float    llog[STEPS * 8];                // all logits, consumed in epilogue

    // ---- coalesced fragment load: 16 contiguous u4/thread (64 dwords) ----
    const uint4* wf = wsf + t0 * 16;
    half8_t bf0[4], bf1[4], bf2[4], bf3[4];
#pragma unroll
    for (int kc = 0; kc < 4; ++kc) {                    // FULL unroll (R6 lesson)
        bf0[kc] = __builtin_bit_cast(half8_t, wf[kc * 4 + 0]);
        bf1[kc] = __builtin_bit_cast(half8_t, wf[kc * 4 + 1]);
        bf2[kc] = __builtin_bit_cast(half8_t, wf[kc * 4 + 2]);
        bf3[kc] = __builtin_bit_cast(half8_t, wf[kc * 4 + 3]);
    }

    // ---- stage gates_x (float4 coalesced), fc head (f16 pack), init h ----
    {
        const float4* g4 = (const float4*)wsg;
        float4* sg4 = (float4*)s_gx;
        for (int i = t0; i < STEPS * 128; i += 512) sg4[i] = g4[i];
        const float2* fw2 = (const float2*)fc_W;
        for (int i = t0; i < 24 * 64; i += 512) { float2 w = fw2[i]; s_fcw2[i] = packf2(w.x, w.y); }
        if (t0 < 24) s_fcb[t0] = fc_b[t0];
        if (t0 < 64) hbuf[64 + t0] = 0u;                // h(-1) = 0 (parity 1)
    }
    float c = 0.0f;
    __syncthreads();

    for (int t = 0; t < STEPS; ++t) {
        // ---- h-part gate MFMA: K=128 from hbuf[(t-1)&1] ----
        const uint4* hp4 = (const uint4*)(hbuf + (((t + 1) & 1) << 6));
        floatx4 a0 = {0,0,0,0}, a1 = {0,0,0,0}, a2 = {0,0,0,0}, a3 = {0,0,0,0};
#pragma unroll
        for (int kc = 0; kc < 4; ++kc) {
            uint4 u = hp4[(kc << 2) + quad];            // 16-lane broadcast b128
            half8_t af = __builtin_bit_cast(half8_t, u);
            a0 = __builtin_amdgcn_mfma_f32_16x16x32_f16(af, bf0[kc], a0, 0, 0, 0);
            a1 = __builtin_amdgcn_mfma_f32_16x16x32_f16(af, bf1[kc], a1, 0, 0, 0);
            a2 = __builtin_amdgcn_mfma_f32_16x16x32_f16(af, bf2[kc], a2, 0, 0, 0);
            a3 = __builtin_amdgcn_mfma_f32_16x16x32_f16(af, bf3[kc], a3, 0, 0, 0);
        }

        // ---- heads of step t-1 (waves 6,7 lanes 16-63; independent of MFMA) ----
        if (t >= 1 && wv >= 6 && lane >= 16) {
            const int hd = (wv - 6) * 3 + (lane >> 4) - 1;   // 0..5
            const int li = lane & 15;
            const int hg = ((t - 1) & 3) * 6 + hd;
            const unsigned* hb = hbuf + (((t + 1) & 1) << 6); // h(t-1)
            const unsigned* wp = s_fcw2 + hg * 64 + li * 4;
            float p = fdot2u(hb[li * 4],     wp[0], 0.0f);
            p = fdot2u(hb[li * 4 + 1], wp[1], p);
            p = fdot2u(hb[li * 4 + 2], wp[2], p);
            p = fdot2u(hb[li * 4 + 3], wp[3], p);
            p += __shfl_down(p, 8); p += __shfl_down(p, 4);
            p += __shfl_down(p, 2); p += __shfl_down(p, 1);
            if (li == 0) llog[(t - 1) * 8 + hd] = p + s_fcb[hg];
        }

        // ---- LSTM elementwise, wave-local (lanes 0-15 own cells wv*16+lane) ----
        if (lane < 16) {
            const int base = t * 512 + (wv << 4) + lane;
            float ig = fast_sigmoid(a0[0] + s_gx[base]);
            float fg = fast_sigmoid(a1[0] + s_gx[base + 128]);
            float gg = fast_tanh   (a2[0] + s_gx[base + 256]);
            float og = fast_sigmoid(a3[0] + s_gx[base + 384]);
            c = fg * c + ig * gg;
            float h = og * fast_tanh(c);
            float hpv = __shfl_xor(h, 1);
            if ((lane & 1) == 0)
                hbuf[((t & 1) << 6) + (wv << 3) + (lane >> 1)] = packf2(h, hpv);
        }

        __syncthreads();   // single barrier: h(t), llog(t-1) published
    }

    // ---- epilogue: head(19), then all 20 softmaxes + stores in parallel ----
    if (wv >= 6 && lane >= 16) {
        const int hd = (wv - 6) * 3 + (lane >> 4) - 1;
        const int li = lane & 15;
        const int hg = (19 & 3) * 6 + hd;
        const unsigned* hb = hbuf + 64;                 // h(19), parity 1
        const unsigned* wp = s_fcw2 + hg * 64 + li * 4;
        float p = fdot2u(hb[li * 4],     wp[0], 0.0f);
        p = fdot2u(hb[li * 4 + 1], wp[1], p);
        p = fdot2u(hb[li * 4 + 2], wp[2], p);
        p = fdot2u(hb[li * 4 + 3], wp[3], p);
        p += __shfl_down(p, 8); p += __shfl_down(p, 4);
        p += __shfl_down(p, 2); p += __shfl_down(p, 1);
        if (li == 0) llog[19 * 8 + hd] = p + s_fcb[hg];
    }
    __syncthreads();
    if (t0 < STEPS * 6) {
        const int s = t0 / 6, k = t0 - s * 6;
        const float* L = llog + s * 8;
        float l0 = L[0], l1 = L[1], l2 = L[2], l3 = L[3], l4 = L[4], l5 = L[5];
        float m = fmaxf(fmaxf(fmaxf(l0, l1), fmaxf(l2, l3)), fmaxf(l4, l5));
        float e0 = __expf(l0 - m), e1 = __expf(l1 - m), e2 = __expf(l2 - m);
        float e3 = __expf(l3 - m), e4 = __expf(l4 - m), e5 = __expf(l5 - m);
        float sum = ((e0 + e1) + (e2 + e3)) + (e4 + e5);
        float mine = (k == 0) ? e0 : (k == 1) ? e1 : (k == 2) ? e2
                   : (k == 3) ? e3 : (k == 4) ? e4 : e5;
        out[t0] = mine / sum;
    }
}

// ===== fallback (ws too small): R10 structure with the x-index bug FIXED =====
extern "C" __global__ void __launch_bounds__(512, 1)
nas_policy_fb(const int* __restrict__ net, const float* __restrict__ emb_start,
              const float* __restrict__ emb_keys, const float* __restrict__ fc_W,
              const float* __restrict__ fc_b, const float* __restrict__ W_ih,
              const float* __restrict__ W_hh, const float* __restrict__ b_ih,
              const float* __restrict__ b_hh, float* __restrict__ out)
{
    const int t0 = threadIdx.x, wv = t0 >> 6, lane = t0 & 63;
    const int quad = lane >> 4, lcol = lane & 15;
    __shared__ __align__(16) unsigned xh2[2 * 64];
    __shared__ __align__(16) unsigned s_embk2[24 * 64];
    __shared__ float gates[4 * CELL];
    __shared__ float s_fcW[24 * CELL];
    __shared__ float s_fcb[24];
    __shared__ float logits[2 * 8];
    __shared__ int   s_net[STEPS];
    const int rbase = wv << 6;
    const int r0 = rbase + lcol, r1 = r0 + 16, r2 = r0 + 32, r3 = r0 + 48;
    half8_t bf0[8], bf1[8], bf2[8], bf3[8];
#pragma unroll
    for (int kc = 0; kc < 8; ++kc) {
        const int k0 = (kc << 5) + (quad << 3);
        const float* base = (k0 < 128) ? W_ih + k0 : W_hh + (k0 - 128);
#define LD8(dst, row) { const float4* p4 = (const float4*)(base + (row) * CELL); \
        float4 a = p4[0], b = p4[1]; \
        dst = half8_t{ (_Float16)a.x, (_Float16)a.y, (_Float16)a.z, (_Float16)a.w, \
                       (_Float16)b.x, (_Float16)b.y, (_Float16)b.z, (_Float16)b.w }; }
        LD8(bf0[kc], r0) LD8(bf1[kc], r1) LD8(bf2[kc], r2) LD8(bf3[kc], r3)
#undef LD8
    }
    const float bias0 = b_ih[r0] + b_hh[r0], bias1 = b_ih[r1] + b_hh[r1];
    const float bias2 = b_ih[r2] + b_hh[r2], bias3 = b_ih[r3] + b_hh[r3];
    {
        const float2* ek2 = (const float2*)emb_keys;
        for (int i = t0; i < 24 * 64; i += 512) { float2 v = ek2[i]; s_embk2[i] = packf2(v.x, v.y); }
        for (int i = t0; i < 24 * CELL; i += 512) s_fcW[i] = fc_W[i];
        if (t0 < 24) s_fcb[t0] = fc_b[t0];
        if (t0 < STEPS) s_net[t0] = net[t0];
        if (t0 < 64) { float2 v = ((const float2*)emb_start)[t0];
                       xh2[t0] = packf2(v.x, v.y); xh2[64 + t0] = 0u; }
    }
    float c = 0.0f;
    for (int t = 0; t < STEPS; ++t) {
        __syncthreads();
        floatx4 a0 = {0,0,0,0}, a1 = {0,0,0,0}, a2 = {0,0,0,0}, a3 = {0,0,0,0};
        const uint4* xp = (const uint4*)xh2;
#pragma unroll
        for (int kc = 0; kc < 8; ++kc) {
            half8_t af = __builtin_bit_cast(half8_t, xp[(kc << 2) + quad]);
            a0 = __builtin_amdgcn_mfma_f32_16x16x32_f16(af, bf0[kc], a0, 0, 0, 0);
            a1 = __builtin_amdgcn_mfma_f32_16x16x32_f16(af, bf1[kc], a1, 0, 0, 0);
            a2 = __builtin_amdgcn_mfma_f32_16x16x32_f16(af, bf2[kc], a2, 0, 0, 0);
            a3 = __builtin_amdgcn_mfma_f32_16x16x32_f16(af, bf3[kc], a3, 0, 0, 0);
        }
        if (lane < 16) {
            gates[rbase + lane]      = a0[0] + bias0;
            gates[rbase + 16 + lane] = a1[0] + bias1;
            gates[rbase + 32 + lane] = a2[0] + bias2;
            gates[rbase + 48 + lane] = a3[0] + bias3;
        }
        if (t >= 1 && wv < 6) {
            const int ti = t - 1;
            unsigned hu = xh2[64 + lane];
            const float* Wr = s_fcW + (((ti & 3) * 6) + wv) * CELL;
            typedef _Float16 h2t __attribute__((ext_vector_type(2)));
            h2t hh = __builtin_bit_cast(h2t, hu);
            float p2 = (float)hh[0] * Wr[2 * lane] + (float)hh[1] * Wr[2 * lane + 1];
#pragma unroll
            for (int off = 32; off >= 1; off >>= 1) p2 += __shfl_down(p2, off);
            if (lane == 0) logits[((ti & 1) << 3) + wv] = p2 + s_fcb[(ti & 3) * 6 + wv];
        }
        if (t >= 2 && t0 < 6) {
            const float* L = logits + ((t & 1) << 3);
            float l0 = L[0], l1 = L[1], l2 = L[2], l3 = L[3], l4 = L[4], l5 = L[5];
            float m = fmaxf(fmaxf(fmaxf(l0, l1), fmaxf(l2, l3)), fmaxf(l4, l5));
            float e0 = __expf(l0 - m), e1 = __expf(l1 - m), e2 = __expf(l2 - m);
            float e3 = __expf(l3 - m), e4 = __expf(l4 - m), e5 = __expf(l5 - m);
            float ssum = ((e0 + e1) + (e2 + e3)) + (e4 + e5);
            float mine = (t0 == 0) ? e0 : (t0 == 1) ? e1 : (t0 == 2) ? e2
                       : (t0 == 3) ? e3 : (t0 == 4) ? e4 : e5;
            out[(t - 2) * 6 + t0] = mine / ssum;
        }
        __syncthreads();
        if (t0 < CELL) {
            float ig = fast_sigmoid(gates[t0]);
            float fg = fast_sigmoid(gates[CELL + t0]);
            float gg = fast_tanh(gates[2 * CELL + t0]);
            float og = fast_sigmoid(gates[3 * CELL + t0]);
            c = fg * c + ig * gg;
            float h = og * fast_tanh(c);
            float hpv = __shfl_xor(h, 1);
            if ((t0 & 1) == 0) xh2[64 + (t0 >> 1)] = packf2(h, hpv);
        } else if (wv == 2 && t < STEPS - 1) {
            // FIXED: x(t+1) = emb_keys[key(t), net(t)] (reference carries emb_t)
            xh2[lane] = s_embk2[(((t & 3) * 6) + s_net[t]) * 64 + lane];
        }
    }
    __syncthreads();
    if (wv < 6) {
        unsigned hu = xh2[64 + lane];
        const float* Wr = s_fcW + (((19 & 3) * 6) + wv) * CELL;
        typedef _Float16 h2t __attribute__((ext_vector_type(2)));
        h2t hh = __builtin_bit_cast(h2t, hu);
        float p2 = (float)hh[0] * Wr[2 * lane] + (float)hh[1] * Wr[2 * lane + 1];
#pragma unroll
        for (int off = 32; off >= 1; off >>= 1) p2 += __shfl_down(p2, off);
        if (lane == 0) logits[8 + wv] = p2 + s_fcb[(19 & 3) * 6 + wv];
    }
    if (t0 < 6) {
        const float* L = logits + 0;
        float l0 = L[0], l1 = L[1], l2 = L[2], l3 = L[3], l4 = L[4], l5 = L[5];
        float m = fmaxf(fmaxf(fmaxf(l0, l1), fmaxf(l2, l3)), fmaxf(l4, l5));
        float e0 = __expf(l0 - m), e1 = __expf(l1 - m), e2 = __expf(l2 - m);
        float e3 = __expf(l3 - m), e4 = __expf(l4 - m), e5 = __expf(l5 - m);
        float ssum = ((e0 + e1) + (e2 + e3)) + (e4 + e5);
        float mine = (t0 == 0) ? e0 : (t0 == 1) ? e1 : (t0 == 2) ? e2
                   : (t0 == 3) ? e3 : (t0 == 4) ? e4 : e5;
        out[18 * 6 + t0] = mine / ssum;
    }
    __syncthreads();
    if (t0 < 6) {
        const float* L = logits + 8;
        float l0 = L[0], l1 = L[1], l2 = L[2], l3 = L[3], l4 = L[4], l5 = L[5];
        float m = fmaxf(fmaxf(fmaxf(l0, l1), fmaxf(l2, l3)), fmaxf(l4, l5));
        float e0 = __expf(l0 - m), e1 = __expf(l1 - m), e2 = __expf(l2 - m);
        float e3 = __expf(l3 - m), e4 = __expf(l4 - m), e5 = __expf(l5 - m);
        float ssum = ((e0 + e1) + (e2 + e3)) + (e4 + e5);
        float mine = (t0 == 0) ? e0 : (t0 == 1) ? e1 : (t0 == 2) ? e2
                   : (t0 == 3) ? e3 : (t0 == 4) ? e4 : e5;
        out[19 * 6 + t0] = mine / ssum;
    }
}

extern "C" void kernel_launch(void* const* d_in, const int* in_sizes, int n_in,
                              void* d_out, int out_size, void* d_ws, size_t ws_size,
                              hipStream_t stream) {
    (void)in_sizes; (void)n_in; (void)out_size;
    const int*   net       = (const int*)d_in[0];
    // d_in[1] = reward, unused in forward
    const float* emb_start = (const float*)d_in[2];
    const float* emb_keys  = (const float*)d_in[3];
    const float* fc_W      = (const float*)d_in[4];
    const float* fc_b      = (const float*)d_in[5];
    const float* W_ih      = (const float*)d_in[6];
    const float* W_hh      = (const float*)d_in[7];
    const float* b_ih      = (const float*)d_in[8];
    const float* b_hh      = (const float*)d_in[9];
    float*       out       = (float*)d_out;

    if (ws_size >= (size_t)(131072 + STEPS * 512 * sizeof(float))) {
        uint4* wsf = (uint4*)d_ws;
        float* wsg = (float*)((char*)d_ws + 131072);
        hipLaunchKernelGGL(nas_conv_kernel, dim3(32), dim3(256), 0, stream,
                           W_ih, W_hh, b_ih, b_hh, emb_start, emb_keys, net, wsf, wsg);
        hipLaunchKernelGGL(nas_policy_kernel, dim3(1), dim3(512), 0, stream,
                           fc_W, fc_b, wsf, wsg, out);
    } else {
        hipLaunchKernelGGL(nas_policy_fb, dim3(1), dim3(512), 0, stream,
                           net, emb_start, emb_keys, fc_W, fc_b,
                           W_ih, W_hh, b_ih, b_hh, out);
    }
}

// Round 13
// 105.580 us; speedup vs baseline: 1.0029x; 1.0029x over previous
//
#include <hip/hip_runtime.h>
#include <hip/hip_fp16.h>

#define CELL 128
#define STEPS 20

typedef _Float16 half8_t __attribute__((ext_vector_type(8)));
typedef float    floatx4 __attribute__((ext_vector_type(4)));

__device__ __forceinline__ unsigned packf2(float x, float y) {
    typedef _Float16 h2 __attribute__((ext_vector_type(2)));
    h2 h = { (_Float16)x, (_Float16)y };
    return __builtin_bit_cast(unsigned, h);
}
__device__ __forceinline__ float fdot2u(unsigned a, unsigned b, float c) {
    typedef _Float16 h2 __attribute__((ext_vector_type(2)));
#if __has_builtin(__builtin_amdgcn_fdot2)
    return __builtin_amdgcn_fdot2(__builtin_bit_cast(h2, a), __builtin_bit_cast(h2, b), c, false);
#else
    h2 x = __builtin_bit_cast(h2, a), y = __builtin_bit_cast(h2, b);
    return fmaf((float)x[0], (float)y[0], fmaf((float)x[1], (float)y[1], c));
#endif
}
__device__ __forceinline__ float fast_sigmoid(float x) { return 1.0f / (1.0f + __expf(-x)); }
__device__ __forceinline__ float fast_tanh(float x) {
    return 2.0f / (1.0f + __expf(-2.0f * x)) - 1.0f;
}
__device__ __forceinline__ half8_t cvt8(const float* p) {
    const float4* p4 = (const float4*)p;
    float4 a = p4[0], b = p4[1];
    return half8_t{ (_Float16)a.x, (_Float16)a.y, (_Float16)a.z, (_Float16)a.w,
                    (_Float16)b.x, (_Float16)b.y, (_Float16)b.z, (_Float16)b.w };
}

// SINGLE kernel: prologue computes gates_x[20][512] = W_ih.x(t)+bias via MFMA
// (W_ih frags transient -> discarded before W_hh frags load; peak arch-VGPR
// ~120 < 128, per the R10 model: 8 waves => 256/thread unified, split ~50/50
// arch/AGPR when MFMA present). Loop+epilogue = R12 verbatim (absmax 0.0).
// Frag spec: wave wv, lane: quad=lane>>4, lcol=lane&15; tile tau in [0,4) =
// gate block; row r = tau*128 + wv*16 + lcol; chunk kc: k0 = kc*32 + quad*8.
extern "C" __global__ void __launch_bounds__(512, 1)
nas_policy_kernel(const int* __restrict__ net,
                  const float* __restrict__ emb_start,   // [1][128]
                  const float* __restrict__ emb_keys,    // [4][6][128]
                  const float* __restrict__ fc_W,        // [4][6][128]
                  const float* __restrict__ fc_b,        // [4][6]
                  const float* __restrict__ W_ih,        // [512][128]
                  const float* __restrict__ W_hh,        // [512][128]
                  const float* __restrict__ b_ih,        // [512]
                  const float* __restrict__ b_hh,        // [512]
                  float* __restrict__ out)               // [20][1][6] fp32
{
    const int t0   = threadIdx.x;    // 0..511
    const int wv   = t0 >> 6;
    const int lane = t0 & 63;
    const int quad = lane >> 4;
    const int lcol = lane & 15;

    __shared__ __align__(16) unsigned s_xv2[32 * 68];   // x rows packed half2, stride 68 (pad)
    __shared__ __align__(16) float    s_gx[STEPS * 512];// gates_x incl. bias (40 KB)
    __shared__ __align__(16) unsigned hbuf[2 * 64];     // h packed half2, parity-buffered
    __shared__ unsigned s_fcw2[24 * 64];                // fc_W packed half2
    __shared__ float    s_fcb[24];
    __shared__ float    llog[STEPS * 8];                // all logits -> epilogue

    // ---- stage x rows (m=0: emb_start; m>=1: emb_keys[key(m-1), net(m-1)]) ----
    for (int i = t0; i < STEPS * 64; i += 512) {
        const int m = i >> 6, j = i & 63;
        const float2* src = (m == 0) ? (const float2*)emb_start
            : (const float2*)(emb_keys + ((((m - 1) & 3) * 6) + net[m - 1]) * CELL);
        float2 v = src[j];
        s_xv2[m * 68 + j] = packf2(v.x, v.y);
        // rows 20..31 stay garbage: their MFMA output rows are never stored
    }
    {
        const float2* fw2 = (const float2*)fc_W;
        for (int i = t0; i < 24 * 64; i += 512) { float2 w = fw2[i]; s_fcw2[i] = packf2(w.x, w.y); }
    }
    if (t0 < 24) s_fcb[t0] = fc_b[t0];
    if (t0 < 64) hbuf[64 + t0] = 0u;                    // h(-1) = 0 (parity 1)

    const int rr0 = (wv << 4) + lcol;                   // row base (+ tau*128)
    float biasx[4];
#pragma unroll
    for (int tau = 0; tau < 4; ++tau) {
        const int r = tau * 128 + rr0;
        biasx[tau] = b_ih[r] + b_hh[r];
    }

    __syncthreads();   // s_xv2 ready

    // ---- phase 1: gates_x via MFMA (M-tiles m=0..15, 16..19; W_ih transient) ----
    {
        half8_t bw[4][4];                               // [kc][tau]
#pragma unroll
        for (int kc = 0; kc < 4; ++kc) {
            const int k0 = kc * 32 + quad * 8;
#pragma unroll
            for (int tau = 0; tau < 4; ++tau)
                bw[kc][tau] = cvt8(W_ih + (tau * 128 + rr0) * CELL + k0);
        }
        floatx4 ax0[4] = { {0,0,0,0}, {0,0,0,0}, {0,0,0,0}, {0,0,0,0} };
        floatx4 ax1[4] = { {0,0,0,0}, {0,0,0,0}, {0,0,0,0}, {0,0,0,0} };
#pragma unroll
        for (int kc = 0; kc < 4; ++kc) {
            uint4 u0 = *(const uint4*)&s_xv2[lcol * 68 + kc * 16 + quad * 4];
            uint4 u1 = *(const uint4*)&s_xv2[(16 + lcol) * 68 + kc * 16 + quad * 4];
            half8_t a0f = __builtin_bit_cast(half8_t, u0);
            half8_t a1f = __builtin_bit_cast(half8_t, u1);
#pragma unroll
            for (int tau = 0; tau < 4; ++tau) {
                ax0[tau] = __builtin_amdgcn_mfma_f32_16x16x32_f16(a0f, bw[kc][tau], ax0[tau], 0, 0, 0);
                ax1[tau] = __builtin_amdgcn_mfma_f32_16x16x32_f16(a1f, bw[kc][tau], ax1[tau], 0, 0, 0);
            }
        }
        // C layout: row m = quad*4+reg, col = lcol (m89-verified)
#pragma unroll
        for (int tau = 0; tau < 4; ++tau) {
            const int r = tau * 128 + rr0;
#pragma unroll
            for (int reg = 0; reg < 4; ++reg)
                s_gx[(quad * 4 + reg) * 512 + r] = ax0[tau][reg] + biasx[tau];
            if (quad == 0) {                            // tile1 rows 16..19 only
#pragma unroll
                for (int reg = 0; reg < 4; ++reg)
                    s_gx[(16 + reg) * 512 + r] = ax1[tau][reg] + biasx[tau];
            }
        }
    }
    __builtin_amdgcn_sched_barrier(0);   // keep W_hh frag loads AFTER bw is dead

    // ---- phase 2: W_hh B-fragments (persist through the loop) ----
    half8_t bf0[4], bf1[4], bf2[4], bf3[4];
#pragma unroll
    for (int kc = 0; kc < 4; ++kc) {
        const int k0 = kc * 32 + quad * 8;
        bf0[kc] = cvt8(W_hh + (0 * 128 + rr0) * CELL + k0);
        bf1[kc] = cvt8(W_hh + (1 * 128 + rr0) * CELL + k0);
        bf2[kc] = cvt8(W_hh + (2 * 128 + rr0) * CELL + k0);
        bf3[kc] = cvt8(W_hh + (3 * 128 + rr0) * CELL + k0);
    }

    float c = 0.0f;
    __syncthreads();   // s_gx ready

    // ======== serial recurrence: ONE barrier per step (R12-verified) ========
    for (int t = 0; t < STEPS; ++t) {
        const uint4* hp4 = (const uint4*)(hbuf + (((t + 1) & 1) << 6));   // h(t-1)
        floatx4 a0 = {0,0,0,0}, a1 = {0,0,0,0}, a2 = {0,0,0,0}, a3 = {0,0,0,0};
#pragma unroll
        for (int kc = 0; kc < 4; ++kc) {
            uint4 u = hp4[(kc << 2) + quad];            // 16-lane broadcast b128
            half8_t af = __builtin_bit_cast(half8_t, u);
            a0 = __builtin_amdgcn_mfma_f32_16x16x32_f16(af, bf0[kc], a0, 0, 0, 0);
            a1 = __builtin_amdgcn_mfma_f32_16x16x32_f16(af, bf1[kc], a1, 0, 0, 0);
            a2 = __builtin_amdgcn_mfma_f32_16x16x32_f16(af, bf2[kc], a2, 0, 0, 0);
            a3 = __builtin_amdgcn_mfma_f32_16x16x32_f16(af, bf3[kc], a3, 0, 0, 0);
        }

        // heads of step t-1 (waves 6,7 lanes 16-63)
        if (t >= 1 && wv >= 6 && lane >= 16) {
            const int hd = (wv - 6) * 3 + (lane >> 4) - 1;   // 0..5
            const int li = lane & 15;
            const int hg = ((t - 1) & 3) * 6 + hd;
            const unsigned* hb = hbuf + (((t + 1) & 1) << 6);
            const unsigned* wp = s_fcw2 + hg * 64 + li * 4;
            float p = fdot2u(hb[li * 4],     wp[0], 0.0f);
            p = fdot2u(hb[li * 4 + 1], wp[1], p);
            p = fdot2u(hb[li * 4 + 2], wp[2], p);
            p = fdot2u(hb[li * 4 + 3], wp[3], p);
            p += __shfl_down(p, 8); p += __shfl_down(p, 4);
            p += __shfl_down(p, 2); p += __shfl_down(p, 1);
            if (li == 0) llog[(t - 1) * 8 + hd] = p + s_fcb[hg];
        }

        // LSTM elementwise, wave-local (lanes 0-15 own cells wv*16+lane)
        if (lane < 16) {
            const int base = t * 512 + (wv << 4) + lane;
            float ig = fast_sigmoid(a0[0] + s_gx[base]);
            float fg = fast_sigmoid(a1[0] + s_gx[base + 128]);
            float gg = fast_tanh   (a2[0] + s_gx[base + 256]);
            float og = fast_sigmoid(a3[0] + s_gx[base + 384]);
            c = fg * c + ig * gg;
            float h = og * fast_tanh(c);
            float hpv = __shfl_xor(h, 1);
            if ((lane & 1) == 0)
                hbuf[((t & 1) << 6) + (wv << 3) + (lane >> 1)] = packf2(h, hpv);
        }

        __syncthreads();   // h(t), llog(t-1) published
    }

    // ======== epilogue: head(19) + all 20 softmaxes ========
    if (wv >= 6 && lane >= 16) {
        const int hd = (wv - 6) * 3 + (lane >> 4) - 1;
        const int li = lane & 15;
        const int hg = (19 & 3) * 6 + hd;
        const unsigned* hb = hbuf + 64;                 // h(19), parity 1
        const unsigned* wp = s_fcw2 + hg * 64 + li * 4;
        float p = fdot2u(hb[li * 4],     wp[0], 0.0f);
        p = fdot2u(hb[li * 4 + 1], wp[1], p);
        p = fdot2u(hb[li * 4 + 2], wp[2], p);
        p = fdot2u(hb[li * 4 + 3], wp[3], p);
        p += __shfl_down(p, 8); p += __shfl_down(p, 4);
        p += __shfl_down(p, 2); p += __shfl_down(p, 1);
        if (li == 0) llog[19 * 8 + hd] = p + s_fcb[hg];
    }
    __syncthreads();
    if (t0 < STEPS * 6) {
        const int s = t0 / 6, k = t0 - s * 6;
        const float* L = llog + s * 8;
        float l0 = L[0], l1 = L[1], l2 = L[2], l3 = L[3], l4 = L[4], l5 = L[5];
        float m = fmaxf(fmaxf(fmaxf(l0, l1), fmaxf(l2, l3)), fmaxf(l4, l5));
        float e0 = __expf(l0 - m), e1 = __expf(l1 - m), e2 = __expf(l2 - m);
        float e3 = __expf(l3 - m), e4 = __expf(l4 - m), e5 = __expf(l5 - m);
        float sum = ((e0 + e1) + (e2 + e3)) + (e4 + e5);
        float mine = (k == 0) ? e0 : (k == 1) ? e1 : (k == 2) ? e2
                   : (k == 3) ? e3 : (k == 4) ? e4 : e5;
        out[t0] = mine / sum;
    }
}

extern "C" void kernel_launch(void* const* d_in, const int* in_sizes, int n_in,
                              void* d_out, int out_size, void* d_ws, size_t ws_size,
                              hipStream_t stream) {
    (void)in_sizes; (void)n_in; (void)out_size; (void)d_ws; (void)ws_size;
    const int*   net       = (const int*)d_in[0];
    // d_in[1] = reward, unused in forward
    const float* emb_start = (const float*)d_in[2];
    const float* emb_keys  = (const float*)d_in[3];
    const float* fc_W      = (const float*)d_in[4];
    const float* fc_b      = (const float*)d_in[5];
    const float* W_ih      = (const float*)d_in[6];
    const float* W_hh      = (const float*)d_in[7];
    const float* b_ih      = (const float*)d_in[8];
    const float* b_hh      = (const float*)d_in[9];
    float*       out       = (float*)d_out;

    hipLaunchKernelGGL(nas_policy_kernel, dim3(1), dim3(512), 0, stream,
                       net, emb_start, emb_keys, fc_W, fc_b,
                       W_ih, W_hh, b_ih, b_hh, out);
}

// Round 14
// 99.398 us; speedup vs baseline: 1.0653x; 1.0622x over previous
//
#include <hip/hip_runtime.h>
#include <hip/hip_fp16.h>

#define CELL 128
#define STEPS 20

typedef _Float16 half8_t __attribute__((ext_vector_type(8)));
typedef float    floatx4 __attribute__((ext_vector_type(4)));

__device__ __forceinline__ unsigned packf2(float x, float y) {
    typedef _Float16 h2 __attribute__((ext_vector_type(2)));
    h2 h = { (_Float16)x, (_Float16)y };
    return __builtin_bit_cast(unsigned, h);
}
__device__ __forceinline__ float fdot2u(unsigned a, unsigned b, float c) {
    typedef _Float16 h2 __attribute__((ext_vector_type(2)));
#if __has_builtin(__builtin_amdgcn_fdot2)
    return __builtin_amdgcn_fdot2(__builtin_bit_cast(h2, a), __builtin_bit_cast(h2, b), c, false);
#else
    h2 x = __builtin_bit_cast(h2, a), y = __builtin_bit_cast(h2, b);
    return fmaf((float)x[0], (float)y[0], fmaf((float)x[1], (float)y[1], c));
#endif
}
__device__ __forceinline__ float fastrcp(float x) {
#if __has_builtin(__builtin_amdgcn_rcpf)
    return __builtin_amdgcn_rcpf(x);     // v_rcp_f32, ~1 ulp — ample for 3.5e-3 tol
#else
    return 1.0f / x;
#endif
}
__device__ __forceinline__ half8_t cvt8(const float* p) {
    const float4* p4 = (const float4*)p;
    float4 a = p4[0], b = p4[1];
    return half8_t{ (_Float16)a.x, (_Float16)a.y, (_Float16)a.z, (_Float16)a.w,
                    (_Float16)b.x, (_Float16)b.y, (_Float16)b.z, (_Float16)b.w };
}

// Single kernel, one 512-thread workgroup (8 waves, 1 block/CU).
// Phase 1: gates_x[20][512] = W_ih.x(t)+bias via MFMA (W_ih frags transient).
// Loop: 1 barrier/step; h-part MFMA (K=128, 2-deep chains); full-wave
// activations (lane l computes gate type l>>4 of cell wv*16+(l&15); tanh via
// 2*sigma(2u)-1, v_rcp); i/f/g/o gathered to cell lanes by 3 shuffles.
// Heads of step t-1: wave w<6 head w on lanes 16-31. All softmax in epilogue.
// R4-R13 lessons: full unroll only (no partial - scratch demotion); no
// launch_bounds 2nd arg games (blocks/CU semantics); frags live in AGPRs.
extern "C" __global__ void __launch_bounds__(512, 1)
nas_policy_kernel(const int* __restrict__ net,
                  const float* __restrict__ emb_start,   // [1][128]
                  const float* __restrict__ emb_keys,    // [4][6][128]
                  const float* __restrict__ fc_W,        // [4][6][128]
                  const float* __restrict__ fc_b,        // [4][6]
                  const float* __restrict__ W_ih,        // [512][128]
                  const float* __restrict__ W_hh,        // [512][128]
                  const float* __restrict__ b_ih,        // [512]
                  const float* __restrict__ b_hh,        // [512]
                  float* __restrict__ out)               // [20][1][6] fp32
{
    const int t0   = threadIdx.x;    // 0..511
    const int wv   = t0 >> 6;
    const int lane = t0 & 63;
    const int quad = lane >> 4;
    const int lcol = lane & 15;

    __shared__ __align__(16) unsigned s_xv2[32 * 68];   // x rows packed half2 (pad 68)
    __shared__ __align__(16) float    s_gx[STEPS * 512];// gates_x incl. bias (40 KB)
    __shared__ __align__(16) unsigned hbuf[2 * 64];     // h packed half2, parity
    __shared__ unsigned s_fcw2[24 * 64];                // fc_W packed half2
    __shared__ float    s_fcb[24];
    __shared__ float    llog[STEPS * 8];

    // ---- stage x rows (m=0: emb_start; m>=1: emb_keys[key(m-1), net(m-1)]) ----
    for (int i = t0; i < STEPS * 64; i += 512) {
        const int m = i >> 6, j = i & 63;
        const float2* src = (m == 0) ? (const float2*)emb_start
            : (const float2*)(emb_keys + ((((m - 1) & 3) * 6) + net[m - 1]) * CELL);
        float2 v = src[j];
        s_xv2[m * 68 + j] = packf2(v.x, v.y);
    }
    {
        const float2* fw2 = (const float2*)fc_W;
        for (int i = t0; i < 24 * 64; i += 512) { float2 w = fw2[i]; s_fcw2[i] = packf2(w.x, w.y); }
    }
    if (t0 < 24) s_fcb[t0] = fc_b[t0];
    if (t0 < 64) hbuf[64 + t0] = 0u;                    // h(-1) = 0 (parity 1)

    const int rr0 = (wv << 4) + lcol;
    float biasx[4];
#pragma unroll
    for (int tau = 0; tau < 4; ++tau) {
        const int r = tau * 128 + rr0;
        biasx[tau] = b_ih[r] + b_hh[r];
    }

    __syncthreads();   // s_xv2 ready

    // ---- phase 1: gates_x via MFMA ----
    {
        half8_t bw[4][4];
#pragma unroll
        for (int kc = 0; kc < 4; ++kc) {
            const int k0 = kc * 32 + quad * 8;
#pragma unroll
            for (int tau = 0; tau < 4; ++tau)
                bw[kc][tau] = cvt8(W_ih + (tau * 128 + rr0) * CELL + k0);
        }
        floatx4 ax0[4] = { {0,0,0,0}, {0,0,0,0}, {0,0,0,0}, {0,0,0,0} };
        floatx4 ax1[4] = { {0,0,0,0}, {0,0,0,0}, {0,0,0,0}, {0,0,0,0} };
#pragma unroll
        for (int kc = 0; kc < 4; ++kc) {
            uint4 u0 = *(const uint4*)&s_xv2[lcol * 68 + kc * 16 + quad * 4];
            uint4 u1 = *(const uint4*)&s_xv2[(16 + lcol) * 68 + kc * 16 + quad * 4];
            half8_t a0f = __builtin_bit_cast(half8_t, u0);
            half8_t a1f = __builtin_bit_cast(half8_t, u1);
#pragma unroll
            for (int tau = 0; tau < 4; ++tau) {
                ax0[tau] = __builtin_amdgcn_mfma_f32_16x16x32_f16(a0f, bw[kc][tau], ax0[tau], 0, 0, 0);
                ax1[tau] = __builtin_amdgcn_mfma_f32_16x16x32_f16(a1f, bw[kc][tau], ax1[tau], 0, 0, 0);
            }
        }
#pragma unroll
        for (int tau = 0; tau < 4; ++tau) {
            const int r = tau * 128 + rr0;
#pragma unroll
            for (int reg = 0; reg < 4; ++reg)
                s_gx[(quad * 4 + reg) * 512 + r] = ax0[tau][reg] + biasx[tau];
            if (quad == 0) {
#pragma unroll
                for (int reg = 0; reg < 4; ++reg)
                    s_gx[(16 + reg) * 512 + r] = ax1[tau][reg] + biasx[tau];
            }
        }
    }
    // (no sched_barrier: let the compiler prefetch W_hh frags during phase 1)

    // ---- W_hh B-fragments (persist; live in AGPRs) ----
    half8_t bf0[4], bf1[4], bf2[4], bf3[4];
#pragma unroll
    for (int kc = 0; kc < 4; ++kc) {
        const int k0 = kc * 32 + quad * 8;
        bf0[kc] = cvt8(W_hh + (0 * 128 + rr0) * CELL + k0);
        bf1[kc] = cvt8(W_hh + (1 * 128 + rr0) * CELL + k0);
        bf2[kc] = cvt8(W_hh + (2 * 128 + rr0) * CELL + k0);
        bf3[kc] = cvt8(W_hh + (3 * 128 + rr0) * CELL + k0);
    }

    // per-lane activation constants: quad 2 computes tanh(u) = 2*sigma(2u)-1
    const float ascale = (quad == 2) ? 2.0f : 1.0f;
    const float amul   = (quad == 2) ? 2.0f : 1.0f;
    const float aadd   = (quad == 2) ? -1.0f : 0.0f;

    float c = 0.0f;
    __syncthreads();   // s_gx ready

    // ======== serial recurrence: ONE barrier per step ========
    for (int t = 0; t < STEPS; ++t) {
        const uint4* hp4 = (const uint4*)(hbuf + (((t + 1) & 1) << 6));   // h(t-1)
        // 2-deep MFMA chains (8 independent accumulators)
        floatx4 a0a = {0,0,0,0}, a0b = {0,0,0,0}, a1a = {0,0,0,0}, a1b = {0,0,0,0};
        floatx4 a2a = {0,0,0,0}, a2b = {0,0,0,0}, a3a = {0,0,0,0}, a3b = {0,0,0,0};
        {
            uint4 u0 = hp4[(0 << 2) + quad], u1 = hp4[(1 << 2) + quad];
            uint4 u2 = hp4[(2 << 2) + quad], u3 = hp4[(3 << 2) + quad];
            half8_t f0 = __builtin_bit_cast(half8_t, u0), f1 = __builtin_bit_cast(half8_t, u1);
            half8_t f2 = __builtin_bit_cast(half8_t, u2), f3 = __builtin_bit_cast(half8_t, u3);
            a0a = __builtin_amdgcn_mfma_f32_16x16x32_f16(f0, bf0[0], a0a, 0, 0, 0);
            a1a = __builtin_amdgcn_mfma_f32_16x16x32_f16(f0, bf1[0], a1a, 0, 0, 0);
            a2a = __builtin_amdgcn_mfma_f32_16x16x32_f16(f0, bf2[0], a2a, 0, 0, 0);
            a3a = __builtin_amdgcn_mfma_f32_16x16x32_f16(f0, bf3[0], a3a, 0, 0, 0);
            a0b = __builtin_amdgcn_mfma_f32_16x16x32_f16(f1, bf0[1], a0b, 0, 0, 0);
            a1b = __builtin_amdgcn_mfma_f32_16x16x32_f16(f1, bf1[1], a1b, 0, 0, 0);
            a2b = __builtin_amdgcn_mfma_f32_16x16x32_f16(f1, bf2[1], a2b, 0, 0, 0);
            a3b = __builtin_amdgcn_mfma_f32_16x16x32_f16(f1, bf3[1], a3b, 0, 0, 0);
            a0a = __builtin_amdgcn_mfma_f32_16x16x32_f16(f2, bf0[2], a0a, 0, 0, 0);
            a1a = __builtin_amdgcn_mfma_f32_16x16x32_f16(f2, bf1[2], a1a, 0, 0, 0);
            a2a = __builtin_amdgcn_mfma_f32_16x16x32_f16(f2, bf2[2], a2a, 0, 0, 0);
            a3a = __builtin_amdgcn_mfma_f32_16x16x32_f16(f2, bf3[2], a3a, 0, 0, 0);
            a0b = __builtin_amdgcn_mfma_f32_16x16x32_f16(f3, bf0[3], a0b, 0, 0, 0);
            a1b = __builtin_amdgcn_mfma_f32_16x16x32_f16(f3, bf1[3], a1b, 0, 0, 0);
            a2b = __builtin_amdgcn_mfma_f32_16x16x32_f16(f3, bf2[3], a2b, 0, 0, 0);
            a3b = __builtin_amdgcn_mfma_f32_16x16x32_f16(f3, bf3[3], a3b, 0, 0, 0);
        }

        // heads of step t-1: wave w<6 computes head w on lanes 16-31
        if (t >= 1 && wv < 6 && quad == 1) {
            const int li = lane & 15;
            const int hg = ((t - 1) & 3) * 6 + wv;
            const unsigned* hb = hbuf + (((t + 1) & 1) << 6);
            const unsigned* wp = s_fcw2 + hg * 64 + li * 4;
            float p = fdot2u(hb[li * 4],     wp[0], 0.0f);
            p = fdot2u(hb[li * 4 + 1], wp[1], p);
            p = fdot2u(hb[li * 4 + 2], wp[2], p);
            p = fdot2u(hb[li * 4 + 3], wp[3], p);
            p += __shfl_down(p, 8); p += __shfl_down(p, 4);
            p += __shfl_down(p, 2); p += __shfl_down(p, 1);
            if (li == 0) llog[(t - 1) * 8 + wv] = p + s_fcb[hg];
        }

        // gate value for this lane: type quad, cell wv*16+lcol
        float gsum = (quad == 0) ? (a0a[0] + a0b[0])
                   : (quad == 1) ? (a1a[0] + a1b[0])
                   : (quad == 2) ? (a2a[0] + a2b[0])
                   :               (a3a[0] + a3b[0]);
        float u = gsum + s_gx[t * 512 + quad * 128 + rr0];
        // activation (sigma, or tanh via 2*sigma(2u)-1), v_rcp
        float act = fmaf(amul, fastrcp(1.0f + __expf(-ascale * u)), aadd);

        // gather i,f,g,o to cell-owner lanes 0-15 and update state
        float fg = __shfl(act, lane + 16);
        float gg = __shfl(act, lane + 32);
        float og = __shfl(act, lane + 48);
        if (lane < 16) {
            c = fg * c + act * gg;                       // act = i on lanes 0-15
            float th = fmaf(2.0f, fastrcp(1.0f + __expf(-2.0f * c)), -1.0f);
            float h = og * th;
            float hpv = __shfl_xor(h, 1);
            if ((lane & 1) == 0)
                hbuf[((t & 1) << 6) + (wv << 3) + (lane >> 1)] = packf2(h, hpv);
        }

        __syncthreads();   // h(t), llog(t-1) published
    }

    // ======== epilogue: head(19) + all 20 softmaxes ========
    if (wv < 6 && quad == 1) {
        const int li = lane & 15;
        const int hg = (19 & 3) * 6 + wv;
        const unsigned* hb = hbuf + 64;                 // h(19), parity 1
        const unsigned* wp = s_fcw2 + hg * 64 + li * 4;
        float p = fdot2u(hb[li * 4],     wp[0], 0.0f);
        p = fdot2u(hb[li * 4 + 1], wp[1], p);
        p = fdot2u(hb[li * 4 + 2], wp[2], p);
        p = fdot2u(hb[li * 4 + 3], wp[3], p);
        p += __shfl_down(p, 8); p += __shfl_down(p, 4);
        p += __shfl_down(p, 2); p += __shfl_down(p, 1);
        if (li == 0) llog[19 * 8 + wv] = p + s_fcb[hg];
    }
    __syncthreads();
    if (t0 < STEPS * 6) {
        const int s = t0 / 6, k = t0 - s * 6;
        const float* L = llog + s * 8;
        float l0 = L[0], l1 = L[1], l2 = L[2], l3 = L[3], l4 = L[4], l5 = L[5];
        float m = fmaxf(fmaxf(fmaxf(l0, l1), fmaxf(l2, l3)), fmaxf(l4, l5));
        float e0 = __expf(l0 - m), e1 = __expf(l1 - m), e2 = __expf(l2 - m);
        float e3 = __expf(l3 - m), e4 = __expf(l4 - m), e5 = __expf(l5 - m);
        float sum = ((e0 + e1) + (e2 + e3)) + (e4 + e5);
        float mine = (k == 0) ? e0 : (k == 1) ? e1 : (k == 2) ? e2
                   : (k == 3) ? e3 : (k == 4) ? e4 : e5;
        out[t0] = mine / sum;
    }
}

extern "C" void kernel_launch(void* const* d_in, const int* in_sizes, int n_in,
                              void* d_out, int out_size, void* d_ws, size_t ws_size,
                              hipStream_t stream) {
    (void)in_sizes; (void)n_in; (void)out_size; (void)d_ws; (void)ws_size;
    const int*   net       = (const int*)d_in[0];
    // d_in[1] = reward, unused in forward
    const float* emb_start = (const float*)d_in[2];
    const float* emb_keys  = (const float*)d_in[3];
    const float* fc_W      = (const float*)d_in[4];
    const float* fc_b      = (const float*)d_in[5];
    const float* W_ih      = (const float*)d_in[6];
    const float* W_hh      = (const float*)d_in[7];
    const float* b_ih      = (const float*)d_in[8];
    const float* b_hh      = (const float*)d_in[9];
    float*       out       = (float*)d_out;

    hipLaunchKernelGGL(nas_policy_kernel, dim3(1), dim3(512), 0, stream,
                       net, emb_start, emb_keys, fc_W, fc_b,
                       W_ih, W_hh, b_ih, b_hh, out);
}

// Round 15
// 98.763 us; speedup vs baseline: 1.0721x; 1.0064x over previous
//
#include <hip/hip_runtime.h>
#include <hip/hip_fp16.h>

#define CELL 128
#define STEPS 20

typedef _Float16 half8_t __attribute__((ext_vector_type(8)));
typedef float    floatx4 __attribute__((ext_vector_type(4)));

__device__ __forceinline__ unsigned packf2(float x, float y) {
    typedef _Float16 h2 __attribute__((ext_vector_type(2)));
    h2 h = { (_Float16)x, (_Float16)y };
    return __builtin_bit_cast(unsigned, h);
}
__device__ __forceinline__ float fdot2u(unsigned a, unsigned b, float c) {
    typedef _Float16 h2 __attribute__((ext_vector_type(2)));
#if __has_builtin(__builtin_amdgcn_fdot2)
    return __builtin_amdgcn_fdot2(__builtin_bit_cast(h2, a), __builtin_bit_cast(h2, b), c, false);
#else
    h2 x = __builtin_bit_cast(h2, a), y = __builtin_bit_cast(h2, b);
    return fmaf((float)x[0], (float)y[0], fmaf((float)x[1], (float)y[1], c));
#endif
}
__device__ __forceinline__ float fastrcp(float x) {
#if __has_builtin(__builtin_amdgcn_rcpf)
    return __builtin_amdgcn_rcpf(x);     // v_rcp_f32 — ~1 ulp, ample for 3.5e-3 tol
#else
    return 1.0f / x;
#endif
}
__device__ __forceinline__ float sig_rcp(float x) {       // sigmoid
    return fastrcp(1.0f + __expf(-x));
}
__device__ __forceinline__ float tanh_rcp(float x) {      // tanh = 2*sigma(2x)-1
    return fmaf(2.0f, fastrcp(1.0f + __expf(-2.0f * x)), -1.0f);
}
__device__ __forceinline__ half8_t cvt8(const float* p) {
    const float4* p4 = (const float4*)p;
    float4 a = p4[0], b = p4[1];
    return half8_t{ (_Float16)a.x, (_Float16)a.y, (_Float16)a.z, (_Float16)a.w,
                    (_Float16)b.x, (_Float16)b.y, (_Float16)b.z, (_Float16)b.w };
}

// Single kernel, one 512-thread workgroup (8 waves, 1 block/CU).
// Phase 1: gates_x[20][cell][4] = W_ih.x(t)+bias via MFMA (W_ih frags transient).
// Loop (1 barrier/step), shortest chain found so far:
//   ds_read_b128 h(t-1) + ds_read_b128 gx -> 2-deep MFMA (K=128) ->
//   per-lane FULL elementwise (every lane holds all 4 gates of cell
//   wv*16+(lane&15): C-layout col=lane&15, rows identical under broadcast-A;
//   4 independent exp.rcp pipelined) -> ds_write_b16 h -> barrier.
// No shuffles in the chain (R14's 3-shfl gather + shfl_xor pack removed).
// Heads of t-1 on waves 0-5 quad 1, in the MFMA shadow; softmax in epilogue.
// Lessons: full unroll only; no launch_bounds 2nd-arg games; frags in AGPRs.
extern "C" __global__ void __launch_bounds__(512, 1)
nas_policy_kernel(const int* __restrict__ net,
                  const float* __restrict__ emb_start,   // [1][128]
                  const float* __restrict__ emb_keys,    // [4][6][128]
                  const float* __restrict__ fc_W,        // [4][6][128]
                  const float* __restrict__ fc_b,        // [4][6]
                  const float* __restrict__ W_ih,        // [512][128]
                  const float* __restrict__ W_hh,        // [512][128]
                  const float* __restrict__ b_ih,        // [512]
                  const float* __restrict__ b_hh,        // [512]
                  float* __restrict__ out)               // [20][1][6] fp32
{
    const int t0   = threadIdx.x;    // 0..511
    const int wv   = t0 >> 6;
    const int lane = t0 & 63;
    const int quad = lane >> 4;
    const int lcol = lane & 15;

    __shared__ __align__(16) unsigned  s_xv2[32 * 68];    // x rows packed half2 (pad 68)
    __shared__ __align__(16) float     s_gx[STEPS * 512]; // gates_x [t][cell][4] (40 KB)
    __shared__ __align__(16) _Float16  hbuf[2 * 128];     // h f16, parity-buffered
    __shared__ unsigned s_fcw2[24 * 64];                  // fc_W packed half2
    __shared__ float    s_fcb[24];
    __shared__ float    llog[STEPS * 8];

    // ---- stage x rows (m=0: emb_start; m>=1: emb_keys[key(m-1), net(m-1)]) ----
    for (int i = t0; i < STEPS * 64; i += 512) {
        const int m = i >> 6, j = i & 63;
        const float2* src = (m == 0) ? (const float2*)emb_start
            : (const float2*)(emb_keys + ((((m - 1) & 3) * 6) + net[m - 1]) * CELL);
        float2 v = src[j];
        s_xv2[m * 68 + j] = packf2(v.x, v.y);
    }
    {
        const float2* fw2 = (const float2*)fc_W;
        for (int i = t0; i < 24 * 64; i += 512) { float2 w = fw2[i]; s_fcw2[i] = packf2(w.x, w.y); }
    }
    if (t0 < 24)  s_fcb[t0] = fc_b[t0];
    if (t0 < 128) hbuf[128 + t0] = (_Float16)0.0f;        // h(-1) = 0 (parity 1)

    const int rr0 = (wv << 4) + lcol;                     // this lane's cell / row base
    float biasx[4];
#pragma unroll
    for (int tau = 0; tau < 4; ++tau) {
        const int r = tau * 128 + rr0;
        biasx[tau] = b_ih[r] + b_hh[r];
    }

    __syncthreads();   // s_xv2 ready

    // ---- phase 1: gates_x via MFMA; layout s_gx[m*512 + cell*4 + tau] ----
    {
        half8_t bw[4][4];
#pragma unroll
        for (int kc = 0; kc < 4; ++kc) {
            const int k0 = kc * 32 + quad * 8;
#pragma unroll
            for (int tau = 0; tau < 4; ++tau)
                bw[kc][tau] = cvt8(W_ih + (tau * 128 + rr0) * CELL + k0);
        }
        floatx4 ax0[4] = { {0,0,0,0}, {0,0,0,0}, {0,0,0,0}, {0,0,0,0} };
        floatx4 ax1[4] = { {0,0,0,0}, {0,0,0,0}, {0,0,0,0}, {0,0,0,0} };
#pragma unroll
        for (int kc = 0; kc < 4; ++kc) {
            uint4 u0 = *(const uint4*)&s_xv2[lcol * 68 + kc * 16 + quad * 4];
            uint4 u1 = *(const uint4*)&s_xv2[(16 + lcol) * 68 + kc * 16 + quad * 4];
            half8_t a0f = __builtin_bit_cast(half8_t, u0);
            half8_t a1f = __builtin_bit_cast(half8_t, u1);
#pragma unroll
            for (int tau = 0; tau < 4; ++tau) {
                ax0[tau] = __builtin_amdgcn_mfma_f32_16x16x32_f16(a0f, bw[kc][tau], ax0[tau], 0, 0, 0);
                ax1[tau] = __builtin_amdgcn_mfma_f32_16x16x32_f16(a1f, bw[kc][tau], ax1[tau], 0, 0, 0);
            }
        }
        // C layout: step m = quad*4+reg, gate-row col = lcol
#pragma unroll
        for (int tau = 0; tau < 4; ++tau) {
#pragma unroll
            for (int reg = 0; reg < 4; ++reg)
                s_gx[(quad * 4 + reg) * 512 + rr0 * 4 + tau] = ax0[tau][reg] + biasx[tau];
            if (quad == 0) {
#pragma unroll
                for (int reg = 0; reg < 4; ++reg)
                    s_gx[(16 + reg) * 512 + rr0 * 4 + tau] = ax1[tau][reg] + biasx[tau];
            }
        }
    }

    // ---- W_hh B-fragments (persist; AGPRs) ----
    half8_t bf0[4], bf1[4], bf2[4], bf3[4];
#pragma unroll
    for (int kc = 0; kc < 4; ++kc) {
        const int k0 = kc * 32 + quad * 8;
        bf0[kc] = cvt8(W_hh + (0 * 128 + rr0) * CELL + k0);
        bf1[kc] = cvt8(W_hh + (1 * 128 + rr0) * CELL + k0);
        bf2[kc] = cvt8(W_hh + (2 * 128 + rr0) * CELL + k0);
        bf3[kc] = cvt8(W_hh + (3 * 128 + rr0) * CELL + k0);
    }

    float c = 0.0f;
    __syncthreads();   // s_gx ready

    // ======== serial recurrence: ONE barrier per step ========
    for (int t = 0; t < STEPS; ++t) {
        const uint4* hp4 = (const uint4*)(hbuf + (((t + 1) & 1) << 7));   // h(t-1)
        // step-top LDS reads: gx (this cell, 4 gates) + h chunks
        floatx4 gx = *(const floatx4*)&s_gx[t * 512 + rr0 * 4];
        floatx4 a0a = {0,0,0,0}, a0b = {0,0,0,0}, a1a = {0,0,0,0}, a1b = {0,0,0,0};
        floatx4 a2a = {0,0,0,0}, a2b = {0,0,0,0}, a3a = {0,0,0,0}, a3b = {0,0,0,0};
        {
            uint4 u0 = hp4[(0 << 2) + quad], u1 = hp4[(1 << 2) + quad];
            uint4 u2 = hp4[(2 << 2) + quad], u3 = hp4[(3 << 2) + quad];
            half8_t f0 = __builtin_bit_cast(half8_t, u0), f1 = __builtin_bit_cast(half8_t, u1);
            half8_t f2 = __builtin_bit_cast(half8_t, u2), f3 = __builtin_bit_cast(half8_t, u3);
            a0a = __builtin_amdgcn_mfma_f32_16x16x32_f16(f0, bf0[0], a0a, 0, 0, 0);
            a1a = __builtin_amdgcn_mfma_f32_16x16x32_f16(f0, bf1[0], a1a, 0, 0, 0);
            a2a = __builtin_amdgcn_mfma_f32_16x16x32_f16(f0, bf2[0], a2a, 0, 0, 0);
            a3a = __builtin_amdgcn_mfma_f32_16x16x32_f16(f0, bf3[0], a3a, 0, 0, 0);
            a0b = __builtin_amdgcn_mfma_f32_16x16x32_f16(f1, bf0[1], a0b, 0, 0, 0);
            a1b = __builtin_amdgcn_mfma_f32_16x16x32_f16(f1, bf1[1], a1b, 0, 0, 0);
            a2b = __builtin_amdgcn_mfma_f32_16x16x32_f16(f1, bf2[1], a2b, 0, 0, 0);
            a3b = __builtin_amdgcn_mfma_f32_16x16x32_f16(f1, bf3[1], a3b, 0, 0, 0);
            a0a = __builtin_amdgcn_mfma_f32_16x16x32_f16(f2, bf0[2], a0a, 0, 0, 0);
            a1a = __builtin_amdgcn_mfma_f32_16x16x32_f16(f2, bf1[2], a1a, 0, 0, 0);
            a2a = __builtin_amdgcn_mfma_f32_16x16x32_f16(f2, bf2[2], a2a, 0, 0, 0);
            a3a = __builtin_amdgcn_mfma_f32_16x16x32_f16(f2, bf3[2], a3a, 0, 0, 0);
            a0b = __builtin_amdgcn_mfma_f32_16x16x32_f16(f3, bf0[3], a0b, 0, 0, 0);
            a1b = __builtin_amdgcn_mfma_f32_16x16x32_f16(f3, bf1[3], a1b, 0, 0, 0);
            a2b = __builtin_amdgcn_mfma_f32_16x16x32_f16(f3, bf2[3], a2b, 0, 0, 0);
            a3b = __builtin_amdgcn_mfma_f32_16x16x32_f16(f3, bf3[3], a3b, 0, 0, 0);
        }

        // heads of step t-1: wave w<6 head w on quad-1 lanes (MFMA shadow)
        if (t >= 1 && wv < 6 && quad == 1) {
            const int li = lcol;
            const int hg = ((t - 1) & 3) * 6 + wv;
            const unsigned* hb = (const unsigned*)(hbuf + (((t + 1) & 1) << 7));
            const unsigned* wp = s_fcw2 + hg * 64 + li * 4;
            float p = fdot2u(hb[li * 4],     wp[0], 0.0f);
            p = fdot2u(hb[li * 4 + 1], wp[1], p);
            p = fdot2u(hb[li * 4 + 2], wp[2], p);
            p = fdot2u(hb[li * 4 + 3], wp[3], p);
            p += __shfl_down(p, 8); p += __shfl_down(p, 4);
            p += __shfl_down(p, 2); p += __shfl_down(p, 1);
            if (li == 0) llog[(t - 1) * 8 + wv] = p + s_fcb[hg];
        }

        // full elementwise on EVERY lane (each holds all 4 gates of cell rr0
        // in acc[0]; redundant across quads — no shuffles in the chain)
        {
            float ig = sig_rcp (a0a[0] + a0b[0] + gx[0]);
            float fg = sig_rcp (a1a[0] + a1b[0] + gx[1]);
            float gg = tanh_rcp(a2a[0] + a2b[0] + gx[2]);
            float og = sig_rcp (a3a[0] + a3b[0] + gx[3]);
            c = fg * c + ig * gg;
            float h = og * tanh_rcp(c);
            if (quad == 0)
                hbuf[((t & 1) << 7) + rr0] = (_Float16)h;   // ds_write_b16
        }

        __syncthreads();   // h(t), llog(t-1) published
    }

    // ======== epilogue: head(19) + all 20 softmaxes ========
    if (wv < 6 && quad == 1) {
        const int li = lcol;
        const int hg = (19 & 3) * 6 + wv;
        const unsigned* hb = (const unsigned*)(hbuf + 128);   // h(19), parity 1
        const unsigned* wp = s_fcw2 + hg * 64 + li * 4;
        float p = fdot2u(hb[li * 4],     wp[0], 0.0f);
        p = fdot2u(hb[li * 4 + 1], wp[1], p);
        p = fdot2u(hb[li * 4 + 2], wp[2], p);
        p = fdot2u(hb[li * 4 + 3], wp[3], p);
        p += __shfl_down(p, 8); p += __shfl_down(p, 4);
        p += __shfl_down(p, 2); p += __shfl_down(p, 1);
        if (li == 0) llog[19 * 8 + wv] = p + s_fcb[hg];
    }
    __syncthreads();
    if (t0 < STEPS * 6) {
        const int s = t0 / 6, k = t0 - s * 6;
        const float* L = llog + s * 8;
        float l0 = L[0], l1 = L[1], l2 = L[2], l3 = L[3], l4 = L[4], l5 = L[5];
        float m = fmaxf(fmaxf(fmaxf(l0, l1), fmaxf(l2, l3)), fmaxf(l4, l5));
        float e0 = __expf(l0 - m), e1 = __expf(l1 - m), e2 = __expf(l2 - m);
        float e3 = __expf(l3 - m), e4 = __expf(l4 - m), e5 = __expf(l5 - m);
        float sum = ((e0 + e1) + (e2 + e3)) + (e4 + e5);
        float mine = (k == 0) ? e0 : (k == 1) ? e1 : (k == 2) ? e2
                   : (k == 3) ? e3 : (k == 4) ? e4 : e5;
        out[t0] = mine / sum;
    }
}

extern "C" void kernel_launch(void* const* d_in, const int* in_sizes, int n_in,
                              void* d_out, int out_size, void* d_ws, size_t ws_size,
                              hipStream_t stream) {
    (void)in_sizes; (void)n_in; (void)out_size; (void)d_ws; (void)ws_size;
    const int*   net       = (const int*)d_in[0];
    // d_in[1] = reward, unused in forward
    const float* emb_start = (const float*)d_in[2];
    const float* emb_keys  = (const float*)d_in[3];
    const float* fc_W      = (const float*)d_in[4];
    const float* fc_b      = (const float*)d_in[5];
    const float* W_ih      = (const float*)d_in[6];
    const float* W_hh      = (const float*)d_in[7];
    const float* b_ih      = (const float*)d_in[8];
    const float* b_hh      = (const float*)d_in[9];
    float*       out       = (float*)d_out;

    hipLaunchKernelGGL(nas_policy_kernel, dim3(1), dim3(512), 0, stream,
                       net, emb_start, emb_keys, fc_W, fc_b,
                       W_ih, W_hh, b_ih, b_hh, out);
}